// Round 20
// baseline (185.500 us; speedup 1.0000x reference)
//
#include <hip/hip_runtime.h>
#include <hip/hip_bf16.h>
#include <math.h>

// Problem constants
#define TT    2048
#define HH    8
#define RDIM  32
#define BB    2

typedef float  f4  __attribute__((ext_vector_type(4)));
typedef int    i4  __attribute__((ext_vector_type(4)));
typedef uint   u2  __attribute__((ext_vector_type(2)));
typedef uint   u4  __attribute__((ext_vector_type(4)));
typedef short  s8v __attribute__((ext_vector_type(8)));   // 8 x bf16 bits (4 VGPR)

// round-to-nearest f32 -> bf16 bits
__device__ __forceinline__ uint rnd16(float x) {
    return (__float_as_uint(x) + 0x8000u) >> 16;
}

union v8cast { u4 u; s8v s; };

// ---------------------------------------------------------------------------
// Kernel 0: Wt prep — transpose (Wq|Wk)[1024][256+256] f32 -> Wt[512][1024]
// bf16 (Wt[n][k] = W[k][n]). LDS-tiled 64x64. 1 MB output, L2-resident.
// ---------------------------------------------------------------------------
__global__ __launch_bounds__(256) void wt_prep(
    const float* __restrict__ Wq,
    const float* __restrict__ Wk,
    ushort* __restrict__ Wt)
{
    __shared__ float T[64][68];
    const int k0 = blockIdx.x * 64;
    const int n0 = blockIdx.y * 64;
    const float* W = (n0 < 256) ? Wq : Wk;
    const int nloc = n0 & 255;
    const int tid = threadIdx.x;

    #pragma unroll
    for (int r = 0; r < 4; ++r) {
        int kl  = (tid >> 4) + r * 16;
        int nl4 = (tid & 15) * 4;
        f4 v = *(const f4*)&W[(size_t)(k0 + kl) * 256 + nloc + nl4];
        T[nl4 + 0][kl] = v.x;
        T[nl4 + 1][kl] = v.y;
        T[nl4 + 2][kl] = v.z;
        T[nl4 + 3][kl] = v.w;
    }
    __syncthreads();

    const int nl = tid >> 2;
    const int kq = (tid & 3) * 16;
    u4 o0, o1;
    #pragma unroll
    for (int j = 0; j < 4; ++j) {
        uint lo = rnd16(T[nl][kq + 2 * j]);
        uint hi = rnd16(T[nl][kq + 2 * j + 1]);
        ((uint*)&o0)[j] = (hi << 16) | lo;
    }
    #pragma unroll
    for (int j = 0; j < 4; ++j) {
        uint lo = rnd16(T[nl][kq + 8 + 2 * j]);
        uint hi = rnd16(T[nl][kq + 8 + 2 * j + 1]);
        ((uint*)&o1)[j] = (hi << 16) | lo;
    }
    ushort* dst = Wt + (size_t)(n0 + nl) * 1024 + k0 + kq;
    *(u4*)dst = o0;
    *(u4*)(dst + 8) = o1;
}

// ---------------------------------------------------------------------------
// Kernel 1: MFMA projection + FUSED dead-region zero-fill (R19, unchanged).
// ---------------------------------------------------------------------------
__global__ __launch_bounds__(256) void proj_mfma(
    const float* __restrict__ x,       // [4096][1024] f32
    const ushort* __restrict__ Wt,     // [512][1024] bf16 bits
    ushort* __restrict__ sqb,          // [4096][256] bf16 bits
    ushort* __restrict__ skb,          // [4096][256] bf16 bits
    float* __restrict__ out)           // [B,H,T,T] f32 (dead region only)
{
    const int tid = threadIdx.x;
    const int l   = tid & 63;
    const int w   = __builtin_amdgcn_readfirstlane(tid) >> 6;  // 0..3
    const int cl  = l & 15;
    const int g4  = l >> 4;
    const int m0  = (blockIdx.x * 4 + w) * 16;   // m-tile
    const int n0  = blockIdx.y * 64;             // n-block (64 wide)

    f4 acc0 = {0,0,0,0}, acc1 = {0,0,0,0}, acc2 = {0,0,0,0}, acc3 = {0,0,0,0};

    const float*  xrow = x + (size_t)(m0 + cl) * 1024;
    const ushort* wbase = Wt + (size_t)(n0 + cl) * 1024;

    for (int ks = 0; ks < 32; ++ks) {
        const int k = ks * 32 + g4 * 8;
        f4 xa = *(const f4*)&xrow[k];
        f4 xb2 = *(const f4*)&xrow[k + 4];
        v8cast bf;
        ((uint*)&bf.u)[0] = (rnd16(xa.y) << 16) | rnd16(xa.x);
        ((uint*)&bf.u)[1] = (rnd16(xa.w) << 16) | rnd16(xa.z);
        ((uint*)&bf.u)[2] = (rnd16(xb2.y) << 16) | rnd16(xb2.x);
        ((uint*)&bf.u)[3] = (rnd16(xb2.w) << 16) | rnd16(xb2.z);
        s8v a0 = *(const s8v*)(wbase + 0 * 16 * 1024 + k);
        s8v a1 = *(const s8v*)(wbase + 1 * 16 * 1024 + k);
        s8v a2 = *(const s8v*)(wbase + 2 * 16 * 1024 + k);
        s8v a3 = *(const s8v*)(wbase + 3 * 16 * 1024 + k);
        acc0 = __builtin_amdgcn_mfma_f32_16x16x32_bf16(a0, bf.s, acc0, 0, 0, 0);
        acc1 = __builtin_amdgcn_mfma_f32_16x16x32_bf16(a1, bf.s, acc1, 0, 0, 0);
        acc2 = __builtin_amdgcn_mfma_f32_16x16x32_bf16(a2, bf.s, acc2, 0, 0, 0);
        acc3 = __builtin_amdgcn_mfma_f32_16x16x32_bf16(a3, bf.s, acc3, 0, 0, 0);
    }

    const int m = m0 + cl;
    const int nbase = n0 + g4 * 4;
    ushort* obase = (n0 < 256) ? (sqb + (size_t)m * 256 + nbase)
                               : (skb + (size_t)m * 256 + (nbase - 256));
    f4 accs[4] = {acc0, acc1, acc2, acc3};
    #pragma unroll
    for (int t = 0; t < 4; ++t) {
        u2 pk;
        pk.x = (rnd16(accs[t][1]) << 16) | rnd16(accs[t][0]);
        pk.y = (rnd16(accs[t][3]) << 16) | rnd16(accs[t][2]);
        *(u2*)(obase + t * 16) = pk;
    }

    // ---- fused zero-fill: balanced 4-strip slice per block ----
    {
        const int zb  = blockIdx.y * 64 + blockIdx.x;
        const int zbh = zb & 15;
        const int sp2 = zb >> 4;             // 0..31
        float* ob = out + (size_t)zbh * TT * TT;
        const int ss[4] = {sp2, 63 - sp2, 64 + sp2, 127 - sp2};
        #pragma unroll
        for (int q = 0; q < 4; ++q) {
            const int s  = ss[q];
            const int i0 = s * 16;
            const int zs = (s + 1) * 16;     // first dead col
            for (int r = 0; r < 16; ++r) {
                float* row = &ob[(size_t)(i0 + r) * TT];
                for (int cz = zs + tid * 4; cz < TT; cz += 256 * 4) {
                    f4 zz = {0.f, 0.f, 0.f, 0.f};
                    *(f4*)&row[cz] = zz;     // plain cached full-line stores
                }
            }
        }
    }
}

// ---------------------------------------------------------------------------
// Kernel 2: MFMA scores + mask + gumbel + softmax — BOTH BATCHES PER BLOCK.
// Block = (h, strip-pair). b=0 and b=1 share mask rows: mv loaded ONCE per
// tile and used for both batches (register reuse -> halves the mask stream
// through LLC, -134MB; -17% load instrs per output element).
// p-state: b=0 packed exp in 32 VGPRs; b=1 in LDS (64KB — R16 proved
// p_lds perf-neutral). launch_bounds(512,2) lifts VGPR cap (no spill at
// ~100 live regs); LDS 66KB -> 2 blocks/CU -> 16 waves/CU.
// ---------------------------------------------------------------------------
__global__ __launch_bounds__(512, 2) void score_mfma(
    const ushort* __restrict__ sqb,     // [4096][256] bf16 bits
    const ushort* __restrict__ skb,     // [4096][256] bf16 bits
    const float*  __restrict__ gumbel,  // [B,H,T,T] f32
    const int*    __restrict__ mask,    // [H,T,T] int32 bool
    float* __restrict__ out)            // [B,H,T,T] f32
{
    const int tid = threadIdx.x;
    const int l   = tid & 63;
    const int w   = __builtin_amdgcn_readfirstlane(tid) >> 6;  // wave id 0..7
    const int h   = blockIdx.x & 7;      // 8 h-values
    const int sp  = blockIdx.x >> 3;     // 0..63 strip-pairs
    const int cl  = l & 15;              // C col -> output row i offset
    const int g4  = l >> 4;              // 0..3  -> j sub-block
    const float RS = 0.17677669529663687f;  // 1/sqrt(RD)

    __shared__ u2    p_lds[8][16][64];   // b=1 exp packed: 64 KB
    __shared__ float sums_lds[2][2][8][16];

    // b=0 rows 0..2047, b=1 rows 2048..4095 of sqb/skb
    const ushort* sqbase0 = sqb + h * RDIM + g4 * 8;
    const ushort* sqbase1 = sqbase0 + (size_t)TT * 256;
    const ushort* skbase0 = skb + h * RDIM + g4 * 8;
    const ushort* skbase1 = skbase0 + (size_t)TT * 256;
    const float*  gb0 = gumbel + (size_t)h * TT * TT;
    const float*  gb1 = gb0 + (size_t)HH * TT * TT;
    const int*    mb  = mask + (size_t)h * TT * TT;
    float*        ob0 = out + (size_t)h * TT * TT;
    float*        ob1 = ob0 + (size_t)HH * TT * TT;

    #pragma unroll 1
    for (int half = 0; half < 2; ++half) {
        const int s      = half ? (127 - sp) : sp;
        const int i0     = s * 16;
        const int ntiles = s + 1;        // live 16-col tiles (max 128)
        const int i      = i0 + cl;      // this lane's output row

        // B fragments (sq row i, both batches): strip-invariant
        s8v bfrag0 = *(const s8v*)(sqbase0 + (size_t)i * 256);
        s8v bfrag1 = *(const s8v*)(sqbase1 + (size_t)i * 256);

        const float* grow0 = gb0 + (size_t)i * TT;
        const float* grow1 = gb1 + (size_t)i * TT;
        const int*   mrow  = mb  + (size_t)i * TT;
        float*       orow0 = ob0 + (size_t)i * TT;
        float*       orow1 = ob1 + (size_t)i * TT;

        // ---- pass 1: MFMA x2 + exp, mask loaded ONCE per tile ----
        float sum0 = 0.f, sum1 = 0.f;
        u2 p0[8][2];                      // b=0 exp in registers
        #pragma unroll
        for (int it = 0; it < 8; ++it) {
            const int jt0 = 2 * w + it * 16;   // wave-uniform pair base
            #pragma unroll
            for (int u = 0; u < 2; ++u) {
                const int jt = jt0 + u;
                if (jt < ntiles) {
                    const size_t arow = (size_t)(jt * 16 + cl) * 256;
                    s8v af0 = *(const s8v*)(skbase0 + arow);
                    s8v af1 = *(const s8v*)(skbase1 + arow);
                    const int jb = jt * 16 + g4 * 4;   // 4 consecutive cols
                    i4 mv = *(const i4*)&mrow[jb];     // SHARED by both b
                    f4 gv0 = *(const f4*)&grow0[jb];
                    f4 gv1 = *(const f4*)&grow1[jb];
                    f4 z = {0.f, 0.f, 0.f, 0.f};
                    f4 c0 = __builtin_amdgcn_mfma_f32_16x16x32_bf16(
                                af0, bfrag0, z, 0, 0, 0);
                    f4 c1 = __builtin_amdgcn_mfma_f32_16x16x32_bf16(
                                af1, bfrag1, z, 0, 0, 0);
                    float e00 = (jb + 0 > i || mv.x) ? 0.f : __expf(fmaf(c0[0], RS, gv0.x));
                    float e01 = (jb + 1 > i || mv.y) ? 0.f : __expf(fmaf(c0[1], RS, gv0.y));
                    float e02 = (jb + 2 > i || mv.z) ? 0.f : __expf(fmaf(c0[2], RS, gv0.z));
                    float e03 = (jb + 3 > i || mv.w) ? 0.f : __expf(fmaf(c0[3], RS, gv0.w));
                    float e10 = (jb + 0 > i || mv.x) ? 0.f : __expf(fmaf(c1[0], RS, gv1.x));
                    float e11 = (jb + 1 > i || mv.y) ? 0.f : __expf(fmaf(c1[1], RS, gv1.y));
                    float e12 = (jb + 2 > i || mv.z) ? 0.f : __expf(fmaf(c1[2], RS, gv1.z));
                    float e13 = (jb + 3 > i || mv.w) ? 0.f : __expf(fmaf(c1[3], RS, gv1.w));
                    sum0 += (e00 + e01) + (e02 + e03);
                    sum1 += (e10 + e11) + (e12 + e13);
                    p0[it][u].x = (rnd16(e01) << 16) | rnd16(e00);
                    p0[it][u].y = (rnd16(e03) << 16) | rnd16(e02);
                    u2 pk1;
                    pk1.x = (rnd16(e11) << 16) | rnd16(e10);
                    pk1.y = (rnd16(e13) << 16) | rnd16(e12);
                    p_lds[w][it * 2 + u][l] = pk1;
                }
            }
        }

        // ---- row-sum reduce (both batches), single barrier per half ----
        sum0 += __shfl_xor(sum0, 16);
        sum0 += __shfl_xor(sum0, 32);
        sum1 += __shfl_xor(sum1, 16);
        sum1 += __shfl_xor(sum1, 32);
        if (l < 16) {
            sums_lds[half][0][w][l] = sum0;
            sums_lds[half][1][w][l] = sum1;
        }
        __syncthreads();
        float t0 = 0.f, t1 = 0.f;
        #pragma unroll
        for (int ww = 0; ww < 8; ++ww) {
            t0 += sums_lds[half][0][ww][cl];
            t1 += sums_lds[half][1][ww][cl];
        }
        const float rinv0 = 1.0f / t0;   // diagonal always live -> t > 0
        const float rinv1 = 1.0f / t1;

        // ---- pass 2: unpack + scale + store (b0 from regs, b1 from LDS) ----
        #pragma unroll
        for (int it = 0; it < 8; ++it) {
            const int jt0 = 2 * w + it * 16;
            #pragma unroll
            for (int u = 0; u < 2; ++u) {
                const int jt = jt0 + u;
                if (jt < ntiles) {
                    const int jb = jt * 16 + g4 * 4;
                    f4 v0;
                    v0.x = __uint_as_float(p0[it][u].x << 16) * rinv0;
                    v0.y = __uint_as_float(p0[it][u].x & 0xffff0000u) * rinv0;
                    v0.z = __uint_as_float(p0[it][u].y << 16) * rinv0;
                    v0.w = __uint_as_float(p0[it][u].y & 0xffff0000u) * rinv0;
                    *(f4*)&orow0[jb] = v0;
                    u2 pk1 = p_lds[w][it * 2 + u][l];
                    f4 v1;
                    v1.x = __uint_as_float(pk1.x << 16) * rinv1;
                    v1.y = __uint_as_float(pk1.x & 0xffff0000u) * rinv1;
                    v1.z = __uint_as_float(pk1.y << 16) * rinv1;
                    v1.w = __uint_as_float(pk1.y & 0xffff0000u) * rinv1;
                    *(f4*)&orow1[jb] = v1;
                }
            }
        }
        __syncthreads();                 // p_lds reused by next half
    }
}

extern "C" void kernel_launch(void* const* d_in, const int* in_sizes, int n_in,
                              void* d_out, int out_size, void* d_ws, size_t ws_size,
                              hipStream_t stream) {
    const float* x      = (const float*)d_in[0];
    const int*   bmask  = (const int*)d_in[1];   // bool -> int32 per harness
    const float* gumbel = (const float*)d_in[2];
    const float* Wq     = (const float*)d_in[3];
    const float* Wk     = (const float*)d_in[4];
    float* out = (float*)d_out;

    ushort* sqb = (ushort*)d_ws;                       // 4096*256 bf16 = 2 MB
    ushort* skb = sqb + (size_t)4096 * 256;            // 2 MB
    ushort* Wt  = skb + (size_t)4096 * 256;            // 512*1024 bf16 = 1 MB

    wt_prep<<<dim3(16, 8), 256, 0, stream>>>(Wq, Wk, Wt);

    // projection + fused dead-region zero-fill (plain cached stores)
    proj_mfma<<<dim3(64, 8), 256, 0, stream>>>(x, Wt, sqb, skb, out);

    // 8 h x 64 balanced strip-pairs, both batches per block, 512 thr
    score_mfma<<<512, 512, 0, stream>>>(sqb, skb, gumbel, bmask, out);
}

// Round 21
// 184.755 us; speedup vs baseline: 1.0040x; 1.0040x over previous
//
#include <hip/hip_runtime.h>
#include <hip/hip_bf16.h>
#include <math.h>

// Problem constants
#define TT    2048
#define HH    8
#define RDIM  32
#define BB    2

typedef float  f4  __attribute__((ext_vector_type(4)));
typedef int    i4  __attribute__((ext_vector_type(4)));
typedef uint   u2  __attribute__((ext_vector_type(2)));
typedef uint   u4  __attribute__((ext_vector_type(4)));
typedef short  s8v __attribute__((ext_vector_type(8)));   // 8 x bf16 bits (4 VGPR)

// round-to-nearest f32 -> bf16 bits
__device__ __forceinline__ uint rnd16(float x) {
    return (__float_as_uint(x) + 0x8000u) >> 16;
}

union v8cast { u4 u; s8v s; };

// ---------------------------------------------------------------------------
// Kernel 0: Wt prep — transpose (Wq|Wk)[1024][256+256] f32 -> Wt[512][1024]
// bf16 (Wt[n][k] = W[k][n]). LDS-tiled 64x64. 1 MB output, L2-resident.
// ---------------------------------------------------------------------------
__global__ __launch_bounds__(256) void wt_prep(
    const float* __restrict__ Wq,
    const float* __restrict__ Wk,
    ushort* __restrict__ Wt)
{
    __shared__ float T[64][68];
    const int k0 = blockIdx.x * 64;
    const int n0 = blockIdx.y * 64;
    const float* W = (n0 < 256) ? Wq : Wk;
    const int nloc = n0 & 255;
    const int tid = threadIdx.x;

    #pragma unroll
    for (int r = 0; r < 4; ++r) {
        int kl  = (tid >> 4) + r * 16;
        int nl4 = (tid & 15) * 4;
        f4 v = *(const f4*)&W[(size_t)(k0 + kl) * 256 + nloc + nl4];
        T[nl4 + 0][kl] = v.x;
        T[nl4 + 1][kl] = v.y;
        T[nl4 + 2][kl] = v.z;
        T[nl4 + 3][kl] = v.w;
    }
    __syncthreads();

    const int nl = tid >> 2;
    const int kq = (tid & 3) * 16;
    u4 o0, o1;
    #pragma unroll
    for (int j = 0; j < 4; ++j) {
        uint lo = rnd16(T[nl][kq + 2 * j]);
        uint hi = rnd16(T[nl][kq + 2 * j + 1]);
        ((uint*)&o0)[j] = (hi << 16) | lo;
    }
    #pragma unroll
    for (int j = 0; j < 4; ++j) {
        uint lo = rnd16(T[nl][kq + 8 + 2 * j]);
        uint hi = rnd16(T[nl][kq + 8 + 2 * j + 1]);
        ((uint*)&o1)[j] = (hi << 16) | lo;
    }
    ushort* dst = Wt + (size_t)(n0 + nl) * 1024 + k0 + kq;
    *(u4*)dst = o0;
    *(u4*)(dst + 8) = o1;
}

// ---------------------------------------------------------------------------
// Kernel 1: MFMA projection + FUSED dead-region zero-fill.
// proj: sq/sk[m][n] = sum_k x[m][k] * Wt[n][k]; mfma(A=Wt,B=x), lane owns
// col m, 4 consecutive n. proj is latency-bound (~26us, ~20MB traffic);
// the 134MB causally-dead output fill rides along with PLAIN cached
// full-line stores (R18 evidence: fillBuffer hits 6.4-7 TB/s plain; NT
// stores measured ~2x slower). 512 blocks x balanced 4-strip slice.
// ---------------------------------------------------------------------------
__global__ __launch_bounds__(256) void proj_mfma(
    const float* __restrict__ x,       // [4096][1024] f32
    const ushort* __restrict__ Wt,     // [512][1024] bf16 bits
    ushort* __restrict__ sqb,          // [4096][256] bf16 bits
    ushort* __restrict__ skb,          // [4096][256] bf16 bits
    float* __restrict__ out)           // [B,H,T,T] f32 (dead region only)
{
    const int tid = threadIdx.x;
    const int l   = tid & 63;
    const int w   = __builtin_amdgcn_readfirstlane(tid) >> 6;  // 0..3
    const int cl  = l & 15;
    const int g4  = l >> 4;
    const int m0  = (blockIdx.x * 4 + w) * 16;   // m-tile
    const int n0  = blockIdx.y * 64;             // n-block (64 wide)

    f4 acc0 = {0,0,0,0}, acc1 = {0,0,0,0}, acc2 = {0,0,0,0}, acc3 = {0,0,0,0};

    const float*  xrow = x + (size_t)(m0 + cl) * 1024;
    const ushort* wbase = Wt + (size_t)(n0 + cl) * 1024;

    for (int ks = 0; ks < 32; ++ks) {
        const int k = ks * 32 + g4 * 8;
        f4 xa = *(const f4*)&xrow[k];
        f4 xb2 = *(const f4*)&xrow[k + 4];
        v8cast bf;
        ((uint*)&bf.u)[0] = (rnd16(xa.y) << 16) | rnd16(xa.x);
        ((uint*)&bf.u)[1] = (rnd16(xa.w) << 16) | rnd16(xa.z);
        ((uint*)&bf.u)[2] = (rnd16(xb2.y) << 16) | rnd16(xb2.x);
        ((uint*)&bf.u)[3] = (rnd16(xb2.w) << 16) | rnd16(xb2.z);
        s8v a0 = *(const s8v*)(wbase + 0 * 16 * 1024 + k);
        s8v a1 = *(const s8v*)(wbase + 1 * 16 * 1024 + k);
        s8v a2 = *(const s8v*)(wbase + 2 * 16 * 1024 + k);
        s8v a3 = *(const s8v*)(wbase + 3 * 16 * 1024 + k);
        acc0 = __builtin_amdgcn_mfma_f32_16x16x32_bf16(a0, bf.s, acc0, 0, 0, 0);
        acc1 = __builtin_amdgcn_mfma_f32_16x16x32_bf16(a1, bf.s, acc1, 0, 0, 0);
        acc2 = __builtin_amdgcn_mfma_f32_16x16x32_bf16(a2, bf.s, acc2, 0, 0, 0);
        acc3 = __builtin_amdgcn_mfma_f32_16x16x32_bf16(a3, bf.s, acc3, 0, 0, 0);
    }

    const int m = m0 + cl;
    const int nbase = n0 + g4 * 4;
    ushort* obase = (n0 < 256) ? (sqb + (size_t)m * 256 + nbase)
                               : (skb + (size_t)m * 256 + (nbase - 256));
    f4 accs[4] = {acc0, acc1, acc2, acc3};
    #pragma unroll
    for (int t = 0; t < 4; ++t) {
        u2 pk;
        pk.x = (rnd16(accs[t][1]) << 16) | rnd16(accs[t][0]);
        pk.y = (rnd16(accs[t][3]) << 16) | rnd16(accs[t][2]);
        *(u2*)(obase + t * 16) = pk;
    }

    // ---- fused zero-fill: balanced 4-strip slice per block ----
    {
        const int zb  = blockIdx.y * 64 + blockIdx.x;
        const int zbh = zb & 15;
        const int sp2 = zb >> 4;             // 0..31
        float* ob = out + (size_t)zbh * TT * TT;
        const int ss[4] = {sp2, 63 - sp2, 64 + sp2, 127 - sp2};
        #pragma unroll
        for (int q = 0; q < 4; ++q) {
            const int s  = ss[q];
            const int i0 = s * 16;
            const int zs = (s + 1) * 16;     // first dead col
            for (int r = 0; r < 16; ++r) {
                float* row = &ob[(size_t)(i0 + r) * TT];
                for (int cz = zs + tid * 4; cz < TT; cz += 256 * 4) {
                    f4 zz = {0.f, 0.f, 0.f, 0.f};
                    *(f4*)&row[cz] = zz;     // plain cached full-line stores
                }
            }
        }
    }
}

// ---------------------------------------------------------------------------
// Kernel 2: MFMA scores + mask + gumbel + softmax (swapped operands).
// R10 structure (best measured), zero-fill removed, single barrier per half
// via double-buffered sums_lds: pass-2 stores of half 0 can overlap pass-1
// loads of half 1 across waves. [R19 configuration — session best 183.4us]
// ---------------------------------------------------------------------------
__global__ __launch_bounds__(512) void score_mfma(
    const ushort* __restrict__ sqb,     // [4096][256] bf16 bits
    const ushort* __restrict__ skb,     // [4096][256] bf16 bits
    const float*  __restrict__ gumbel,  // [B,H,T,T] f32
    const int*    __restrict__ mask,    // [H,T,T] int32 bool
    float* __restrict__ out)            // [B,H,T,T] f32
{
    const int tid = threadIdx.x;
    const int l   = tid & 63;
    const int w   = __builtin_amdgcn_readfirstlane(tid) >> 6;  // wave id 0..7
    const int bh  = blockIdx.x & 15;
    const int sp  = blockIdx.x >> 4;     // 0..63
    const int h   = bh & (HH - 1);
    const int b   = bh >> 3;
    const int cl  = l & 15;              // C col -> output row i offset
    const int g4  = l >> 4;              // 0..3  -> j sub-block
    const float RS = 0.17677669529663687f;  // 1/sqrt(RD)

    __shared__ float sums_lds[2][8][16]; // double-buffered: one barrier/half

    const ushort* sqbase = sqb + ((size_t)b * TT) * 256 + h * RDIM + g4 * 8;
    const ushort* skbase = skb + ((size_t)b * TT) * 256 + h * RDIM + g4 * 8;
    const float*  gb = gumbel + (size_t)bh * TT * TT;
    const int*    mb = mask + (size_t)h * TT * TT;
    float*        ob = out + (size_t)bh * TT * TT;

    #pragma unroll 1
    for (int half = 0; half < 2; ++half) {
        const int s      = half ? (127 - sp) : sp;
        const int i0     = s * 16;
        const int ntiles = s + 1;        // live 16-col tiles (max 128)
        const int i      = i0 + cl;      // this lane's output row

        // B fragment (sq row i): strip-invariant
        s8v bfrag = *(const s8v*)(sqbase + (size_t)i * 256);

        const float* grow = gb + (size_t)i * TT;
        const int*   mrow = mb + (size_t)i * TT;
        float*       orow = ob + (size_t)i * TT;

        // ---- pass 1: MFMA + exp, pack bf16, accumulate row sum ----
        float sum = 0.f;
        u2 p[8][2];
        #pragma unroll
        for (int it = 0; it < 8; ++it) {
            const int jt0 = 2 * w + it * 16;   // wave-uniform pair base
            #pragma unroll
            for (int u = 0; u < 2; ++u) {
                const int jt = jt0 + u;
                if (jt < ntiles) {
                    // A fragment (sk row j): row = jt*16 + (lane&15)
                    s8v afrag = *(const s8v*)(skbase + (size_t)(jt * 16 + cl) * 256);
                    f4 z = {0.f, 0.f, 0.f, 0.f};
                    f4 c = __builtin_amdgcn_mfma_f32_16x16x32_bf16(
                               afrag, bfrag, z, 0, 0, 0);
                    const int jb = jt * 16 + g4 * 4;   // 4 consecutive cols
                    f4 gv = *(const f4*)&grow[jb];
                    i4 mv = *(const i4*)&mrow[jb];
                    float e0 = (jb + 0 > i || mv.x) ? 0.f : __expf(fmaf(c[0], RS, gv.x));
                    float e1 = (jb + 1 > i || mv.y) ? 0.f : __expf(fmaf(c[1], RS, gv.y));
                    float e2 = (jb + 2 > i || mv.z) ? 0.f : __expf(fmaf(c[2], RS, gv.z));
                    float e3 = (jb + 3 > i || mv.w) ? 0.f : __expf(fmaf(c[3], RS, gv.w));
                    sum += (e0 + e1) + (e2 + e3);
                    p[it][u].x = (rnd16(e1) << 16) | rnd16(e0);
                    p[it][u].y = (rnd16(e3) << 16) | rnd16(e2);
                }
            }
        }

        // ---- row-sum reduce: across g4 groups, then across waves ----
        sum += __shfl_xor(sum, 16);
        sum += __shfl_xor(sum, 32);
        if (l < 16) sums_lds[half][w][l] = sum;
        __syncthreads();                 // single barrier per half
        float t = 0.f;
        #pragma unroll
        for (int ww = 0; ww < 8; ++ww) t += sums_lds[half][ww][cl];
        const float rinv = 1.0f / t;     // diagonal always live -> t > 0

        // ---- pass 2: unpack + scale + store (plain cached stores) ----
        #pragma unroll
        for (int it = 0; it < 8; ++it) {
            const int jt0 = 2 * w + it * 16;
            #pragma unroll
            for (int u = 0; u < 2; ++u) {
                const int jt = jt0 + u;
                if (jt < ntiles) {
                    const int jb = jt * 16 + g4 * 4;
                    f4 v;
                    v.x = __uint_as_float(p[it][u].x << 16) * rinv;
                    v.y = __uint_as_float(p[it][u].x & 0xffff0000u) * rinv;
                    v.z = __uint_as_float(p[it][u].y << 16) * rinv;
                    v.w = __uint_as_float(p[it][u].y & 0xffff0000u) * rinv;
                    *(f4*)&orow[jb] = v;
                }
            }
        }
    }
}

extern "C" void kernel_launch(void* const* d_in, const int* in_sizes, int n_in,
                              void* d_out, int out_size, void* d_ws, size_t ws_size,
                              hipStream_t stream) {
    const float* x      = (const float*)d_in[0];
    const int*   bmask  = (const int*)d_in[1];   // bool -> int32 per harness
    const float* gumbel = (const float*)d_in[2];
    const float* Wq     = (const float*)d_in[3];
    const float* Wk     = (const float*)d_in[4];
    float* out = (float*)d_out;

    ushort* sqb = (ushort*)d_ws;                       // 4096*256 bf16 = 2 MB
    ushort* skb = sqb + (size_t)4096 * 256;            // 2 MB
    ushort* Wt  = skb + (size_t)4096 * 256;            // 512*1024 bf16 = 1 MB

    wt_prep<<<dim3(16, 8), 256, 0, stream>>>(Wq, Wk, Wt);

    // projection + fused dead-region zero-fill (plain cached stores)
    proj_mfma<<<dim3(64, 8), 256, 0, stream>>>(x, Wt, sqb, skb, out);

    // 16 bh x 64 balanced strip-pairs, 512 thr (8 waves) each
    score_mfma<<<1024, 512, 0, stream>>>(sqb, skb, gumbel, bmask, out);
}